// Round 5
// baseline (67194.409 us; speedup 1.0000x reference)
//
#include <hip/hip_runtime.h>
#include <hip/hip_cooperative_groups.h>
#include <stdint.h>

namespace cg = cooperative_groups;
typedef unsigned long long u64;

#define BATCH 32
#define NPTS  131072
#define KOUT  1024
#define NBLK  8                       // blocks per batch
#define TPB   1024
#define PPT   (NPTS / (NBLK * TPB))   // 16 points per thread
#define NWAVES (TPB / 64)

__global__ __launch_bounds__(TPB, 4) void fps_kernel(
    const float* __restrict__ points,   // B*N*3 f32
    const int*   __restrict__ init_idx, // B
    float*       __restrict__ out,      // B*K*3 f32
    u64*         __restrict__ distw,    // [2][BATCH][NBLK] f64 bits of block-best dist
    u64*         __restrict__ idxw)     // [2][BATCH][NBLK] block-best idx
{
    cg::grid_group grid = cg::this_grid();

    const int gid = blockIdx.x;
    // Swizzle: a batch's 8 blocks share gid%8 (likely same XCD). Bijective.
    const int b   = (gid >> 6) * 8 + (gid & 7);
    const int blk = (gid & 63) >> 3;
    const int tid = threadIdx.x;
    const float* bp = points + (size_t)b * NPTS * 3;

    // Persistent per-thread state: 16 points (f32, exact) + 16 running dists (f64).
    float  px[PPT], py[PPT], pz[PPT];
    double dist[PPT];
    const int nbase = blk * (NPTS / NBLK) + tid;   // + j*TPB, strided for coalescing
#pragma unroll
    for (int j = 0; j < PPT; ++j) {
        int n = nbase + j * TPB;
        px[j]   = bp[(size_t)n * 3 + 0];
        py[j]   = bp[(size_t)n * 3 + 1];
        pz[j]   = bp[(size_t)n * 3 + 2];
        dist[j] = 1e10;   // INF
    }

    __shared__ float  s_last[3];
    __shared__ double s_wd[NWAVES];
    __shared__ int    s_wi[NWAVES];

    const int last = init_idx[b];
    if (blk == 0 && tid < 3) {
        out[((size_t)b * KOUT) * 3 + tid] = bp[(size_t)last * 3 + tid];
    }
    float lx = bp[(size_t)last * 3 + 0];
    float ly = bp[(size_t)last * 3 + 1];
    float lz = bp[(size_t)last * 3 + 2];

    for (int it = 0; it < KOUT - 1; ++it) {
        const double lxd = (double)lx, lyd = (double)ly, lzd = (double)lz;

        // --- register-local dist update + argmax.
        // f64: dx exact, dx*dx exact (24x24<=53 bits), sum rounds once per add
        // => bit-identical to a numpy float64 reference regardless of fma.
        double bestd = -1.0;
        int    besti = 0;
#pragma unroll
        for (int j = 0; j < PPT; ++j) {
            double dx = (double)px[j] - lxd;
            double dy = (double)py[j] - lyd;
            double dz = (double)pz[j] - lzd;
            double d2 = dx * dx + dy * dy + dz * dz;
            double nd = fmin(dist[j], d2);
            dist[j] = nd;
            if (nd > bestd) { bestd = nd; besti = nbase + j * TPB; }  // ascending idx => first max
        }

        // --- wave butterfly reduce (64 lanes), (dist,idx) lexicographic, first-max ---
#pragma unroll
        for (int off = 32; off > 0; off >>= 1) {
            double od = __shfl_xor(bestd, off, 64);
            int    oi = __shfl_xor(besti, off, 64);
            if (od > bestd || (od == bestd && oi < besti)) { bestd = od; besti = oi; }
        }
        const int wid  = tid >> 6;
        const int lane = tid & 63;
        if (lane == 0) { s_wd[wid] = bestd; s_wi[wid] = besti; }
        __syncthreads();

        // --- block reduce + publish this block's candidate ---
        if (tid == 0) {
            double vd = s_wd[0];
            int    vi = s_wi[0];
#pragma unroll
            for (int w = 1; w < NWAVES; ++w) {
                double od = s_wd[w]; int oi = s_wi[w];
                if (od > vd || (od == vd && oi < vi)) { vd = od; vi = oi; }
            }
            size_t s = ((size_t)(it & 1) * BATCH + b) * NBLK + blk;
            __hip_atomic_store(&distw[s], (u64)__double_as_longlong(vd),
                               __ATOMIC_RELEASE, __HIP_MEMORY_SCOPE_AGENT);
            __hip_atomic_store(&idxw[s], (u64)(uint32_t)vi,
                               __ATOMIC_RELEASE, __HIP_MEMORY_SCOPE_AGENT);
        }

        grid.sync();   // all 256 blocks: publishes visible everywhere

        if (tid == 0) {
            size_t sbase = ((size_t)(it & 1) * BATCH + b) * NBLK;
            double vd = -1.0;
            int    vi = 0x7FFFFFFF;
#pragma unroll
            for (int w = 0; w < NBLK; ++w) {
                u64 db = __hip_atomic_load(&distw[sbase + w], __ATOMIC_ACQUIRE, __HIP_MEMORY_SCOPE_AGENT);
                u64 ib = __hip_atomic_load(&idxw[sbase + w],  __ATOMIC_ACQUIRE, __HIP_MEMORY_SCOPE_AGENT);
                double od = __longlong_as_double((long long)db);
                int    oi = (int)(uint32_t)ib;
                if (od > vd || (od == vd && oi < vi)) { vd = od; vi = oi; }
            }
            float wx = bp[(size_t)vi * 3 + 0];
            float wy = bp[(size_t)vi * 3 + 1];
            float wz = bp[(size_t)vi * 3 + 2];
            s_last[0] = wx; s_last[1] = wy; s_last[2] = wz;
            if (blk == 0) {
                size_t o_ = ((size_t)b * KOUT + (it + 1)) * 3;
                out[o_ + 0] = wx; out[o_ + 1] = wy; out[o_ + 2] = wz;
            }
        }
        __syncthreads();
        lx = s_last[0]; ly = s_last[1]; lz = s_last[2];
    }
}

extern "C" void kernel_launch(void* const* d_in, const int* in_sizes, int n_in,
                              void* d_out, int out_size, void* d_ws, size_t ws_size,
                              hipStream_t stream) {
    const float* points   = (const float*)d_in[0];
    const int*   init_idx = (const int*)d_in[1];
    float*       out      = (float*)d_out;

    u64* distw = (u64*)d_ws;                              // 2*32*8*8 = 4 KB
    u64* idxw  = distw + 2 * BATCH * NBLK;                // 4 KB

    void* args[] = { (void*)&points, (void*)&init_idx, (void*)&out,
                     (void*)&distw, (void*)&idxw };
    hipLaunchCooperativeKernel((const void*)fps_kernel,
                               dim3(BATCH * NBLK), dim3(TPB),
                               args, 0, stream);
}

// Round 6
// 14608.151 us; speedup vs baseline: 4.5998x; 4.5998x over previous
//
#include <hip/hip_runtime.h>
#include <stdint.h>

typedef unsigned long long u64;

#define BATCH 32
#define NPTS  131072
#define KOUT  1024
#define NBLK  8                       // blocks per batch
#define TPB   1024
#define PPT   (NPTS / (NBLK * TPB))   // 16 points per thread
#define NWAVES (TPB / 64)

// One publication slot per (parity, batch, block). 32 B.
// tag = ((it+1)<<32) | best_idx, release-stored LAST. Parity double-buffer:
// slot[p] for iteration it (p=it&1) is only overwritten at it+2, by which time
// every peer has consumed it (publishing it+1 requires having read all of it).
// 0xAA poison never matches a valid tag -> no zeroing prologue needed.
struct __align__(32) Slot {
    u64      tag;
    u64      dbits;     // f64 bits of block-best dist
    float    x, y, z;   // coords of block-best point (rides along)
    uint32_t pad;
};

__global__ __launch_bounds__(TPB, 4) void fps_kernel(
    const float* __restrict__ points,   // B*N*3 f32
    const int*   __restrict__ init_idx, // B
    float*       __restrict__ out,      // B*K*3 f32
    Slot*        __restrict__ slots)    // [2][BATCH][NBLK]
{
    const int gid = blockIdx.x;
    // Swizzle: a batch's 8 blocks share gid%8 (likely same XCD). Bijective.
    const int b   = (gid >> 6) * 8 + (gid & 7);
    const int blk = (gid & 63) >> 3;
    const int tid = threadIdx.x;
    const float* bp = points + (size_t)b * NPTS * 3;

    // Persistent per-thread state: 16 points (f32) + 16 running dists (f64).
    float  px[PPT], py[PPT], pz[PPT];
    double dist[PPT];
    const int nbase = blk * (NPTS / NBLK) + tid;   // + j*TPB, strided for coalescing
#pragma unroll
    for (int j = 0; j < PPT; ++j) {
        int n = nbase + j * TPB;
        px[j]   = bp[(size_t)n * 3 + 0];
        py[j]   = bp[(size_t)n * 3 + 1];
        pz[j]   = bp[(size_t)n * 3 + 2];
        dist[j] = 1e10;   // INF
    }

    __shared__ float  s_last[3];
    __shared__ double s_wd[NWAVES];
    __shared__ int    s_wi[NWAVES];
    __shared__ float  s_wx[NWAVES], s_wy[NWAVES], s_wz[NWAVES];

    const int last = init_idx[b];
    if (blk == 0 && tid < 3) {
        out[((size_t)b * KOUT) * 3 + tid] = bp[(size_t)last * 3 + tid];
    }
    float lx = bp[(size_t)last * 3 + 0];
    float ly = bp[(size_t)last * 3 + 1];
    float lz = bp[(size_t)last * 3 + 2];

    for (int it = 0; it < KOUT - 1; ++it) {
        const double lxd = (double)lx, lyd = (double)ly, lzd = (double)lz;

        // --- register-local dist update + argmax (f64, bit-identical to np float64;
        //     DO NOT alter the arithmetic expression tree — validated absmax 0.0) ---
        double bestd = -1.0;
        int    besti = 0;
        float  bx = 0.f, by = 0.f, bz = 0.f;
#pragma unroll
        for (int j = 0; j < PPT; ++j) {
            double dx = (double)px[j] - lxd;
            double dy = (double)py[j] - lyd;
            double dz = (double)pz[j] - lzd;
            double d2 = dx * dx + dy * dy + dz * dz;
            double nd = fmin(dist[j], d2);
            dist[j] = nd;
            if (nd > bestd) {
                bestd = nd; besti = nbase + j * TPB;   // ascending idx => first max
                bx = px[j]; by = py[j]; bz = pz[j];
            }
        }

        // --- wave butterfly reduce (64 lanes), (dist,idx) lexicographic, coords ride ---
#pragma unroll
        for (int off = 32; off > 0; off >>= 1) {
            double od = __shfl_xor(bestd, off, 64);
            int    oi = __shfl_xor(besti, off, 64);
            float  ox = __shfl_xor(bx, off, 64);
            float  oy = __shfl_xor(by, off, 64);
            float  oz = __shfl_xor(bz, off, 64);
            if (od > bestd || (od == bestd && oi < besti)) {
                bestd = od; besti = oi; bx = ox; by = oy; bz = oz;
            }
        }
        const int wid  = tid >> 6;
        const int lane = tid & 63;
        if (lane == 0) {
            s_wd[wid] = bestd; s_wi[wid] = besti;
            s_wx[wid] = bx; s_wy[wid] = by; s_wz[wid] = bz;
        }
        __syncthreads();   // (A)

        Slot* sb = &slots[((size_t)(it & 1) * BATCH + b) * NBLK];

        // --- block reduce + publish this block's candidate (tid0) ---
        if (tid == 0) {
            double vd = s_wd[0]; int vi = s_wi[0];
            float  vx = s_wx[0], vy = s_wy[0], vz = s_wz[0];
#pragma unroll
            for (int w = 1; w < NWAVES; ++w) {
                double od = s_wd[w]; int oi = s_wi[w];
                if (od > vd || (od == vd && oi < vi)) {
                    vd = od; vi = oi; vx = s_wx[w]; vy = s_wy[w]; vz = s_wz[w];
                }
            }
            Slot* s = sb + blk;
            s->dbits = (u64)__double_as_longlong(vd);
            s->x = vx; s->y = vy; s->z = vz;
            __hip_atomic_store(&s->tag,
                               ((u64)(uint32_t)(it + 1) << 32) | (uint32_t)vi,
                               __ATOMIC_RELEASE, __HIP_MEMORY_SCOPE_AGENT);
        }

        // --- wave-parallel gather: lanes 0..7 each spin one peer slot ---
        if (tid < NBLK) {
            Slot* s = sb + tid;
            u64 t;
            do {
                t = __hip_atomic_load(&s->tag, __ATOMIC_ACQUIRE, __HIP_MEMORY_SCOPE_AGENT);
            } while ((uint32_t)(t >> 32) != (uint32_t)(it + 1));
            double vd = __longlong_as_double((long long)s->dbits);
            int    vi = (int)(uint32_t)t;
            float  vx = s->x, vy = s->y, vz = s->z;
#pragma unroll
            for (int off = 4; off > 0; off >>= 1) {
                double od = __shfl_xor(vd, off, 64);
                int    oi = __shfl_xor(vi, off, 64);
                float  ox = __shfl_xor(vx, off, 64);
                float  oy = __shfl_xor(vy, off, 64);
                float  oz = __shfl_xor(vz, off, 64);
                if (od > vd || (od == vd && oi < vi)) {
                    vd = od; vi = oi; vx = ox; vy = oy; vz = oz;
                }
            }
            if (tid == 0) {
                s_last[0] = vx; s_last[1] = vy; s_last[2] = vz;
                if (blk == 0) {
                    size_t o_ = ((size_t)b * KOUT + (it + 1)) * 3;
                    out[o_ + 0] = vx; out[o_ + 1] = vy; out[o_ + 2] = vz;
                }
            }
        }
        __syncthreads();   // (B)
        lx = s_last[0]; ly = s_last[1]; lz = s_last[2];
    }
}

extern "C" void kernel_launch(void* const* d_in, const int* in_sizes, int n_in,
                              void* d_out, int out_size, void* d_ws, size_t ws_size,
                              hipStream_t stream) {
    const float* points   = (const float*)d_in[0];
    const int*   init_idx = (const int*)d_in[1];
    float*       out      = (float*)d_out;
    Slot*        slots    = (Slot*)d_ws;   // 2*32*8*32 B = 16 KB

    void* args[] = { (void*)&points, (void*)&init_idx, (void*)&out, (void*)&slots };
    // Cooperative launch solely for the co-residency guarantee (no grid.sync used).
    hipLaunchCooperativeKernel((const void*)fps_kernel,
                               dim3(BATCH * NBLK), dim3(TPB),
                               args, 0, stream);
}

// Round 7
// 11068.414 us; speedup vs baseline: 6.0708x; 1.3198x over previous
//
#include <hip/hip_runtime.h>
#include <stdint.h>

typedef unsigned long long u64;

#define BATCH 32
#define NPTS  131072
#define KOUT  1024
#define NBLK  8                       // blocks per batch
#define TPB   512
#define PPT   (NPTS / (NBLK * TPB))   // 32 points per thread
#define NWAVES (TPB / 64)             // 8

// One publication slot per (parity, batch, block). 32 B.
// tag = ((it+1)<<32) | best_idx, release-stored LAST. Parity double-buffer:
// slot[p] for iteration it (p=it&1) is only overwritten at it+2, by which time
// every peer has provably consumed it. 0xAA poison never matches a valid tag.
struct __align__(32) Slot {
    u64      tag;
    u64      dbits;     // f64 bits of block-best dist
    float    x, y, z;   // coords of block-best point (rides along)
    uint32_t pad;
};

__global__ __launch_bounds__(TPB, 2) void fps_kernel(
    const float* __restrict__ points,   // B*N*3 f32
    const int*   __restrict__ init_idx, // B
    float*       __restrict__ out,      // B*K*3 f32
    Slot*        __restrict__ slots)    // [2][BATCH][NBLK]
{
    const int gid = blockIdx.x;
    // Swizzle: a batch's 8 blocks share gid%8 (likely same XCD). Bijective.
    const int b   = (gid >> 6) * 8 + (gid & 7);
    const int blk = (gid & 63) >> 3;
    const int tid = threadIdx.x;
    const float* bp = points + (size_t)b * NPTS * 3;

    // Persistent per-thread state: 32 points (f32, 96 VGPR) + 32 dists (f64, 64 VGPR).
    // TPB=512 -> 1 block/CU -> VGPR cap 256: everything stays in registers.
    float  px[PPT], py[PPT], pz[PPT];
    double dist[PPT];
    const int nbase = blk * (NPTS / NBLK) + tid;   // + j*TPB, strided for coalescing
#pragma unroll
    for (int j = 0; j < PPT; ++j) {
        int n = nbase + j * TPB;
        px[j]   = bp[(size_t)n * 3 + 0];
        py[j]   = bp[(size_t)n * 3 + 1];
        pz[j]   = bp[(size_t)n * 3 + 2];
        dist[j] = 1e10;   // INF
    }

    __shared__ float  s_last[3];
    __shared__ double s_wd[NWAVES];
    __shared__ int    s_wi[NWAVES];
    __shared__ float  s_wx[NWAVES], s_wy[NWAVES], s_wz[NWAVES];

    const int last = init_idx[b];
    if (blk == 0 && tid < 3) {
        out[((size_t)b * KOUT) * 3 + tid] = bp[(size_t)last * 3 + tid];
    }
    float lx = bp[(size_t)last * 3 + 0];
    float ly = bp[(size_t)last * 3 + 1];
    float lz = bp[(size_t)last * 3 + 2];

    for (int it = 0; it < KOUT - 1; ++it) {
        const double lxd = (double)lx, lyd = (double)ly, lzd = (double)lz;

        // --- register-local dist update + argmax (f64, bit-identical to np float64;
        //     DO NOT alter the arithmetic expression tree — validated absmax 0.0) ---
        double bestd = -1.0;
        int    besti = 0;
        float  bx = 0.f, by = 0.f, bz = 0.f;
#pragma unroll
        for (int j = 0; j < PPT; ++j) {
            double dx = (double)px[j] - lxd;
            double dy = (double)py[j] - lyd;
            double dz = (double)pz[j] - lzd;
            double d2 = dx * dx + dy * dy + dz * dz;
            double nd = fmin(dist[j], d2);
            dist[j] = nd;
            if (nd > bestd) {
                bestd = nd; besti = nbase + j * TPB;   // ascending idx => first max
                bx = px[j]; by = py[j]; bz = pz[j];
            }
        }

        // --- wave butterfly reduce (64 lanes), (dist,idx) lexicographic, coords ride ---
#pragma unroll
        for (int off = 32; off > 0; off >>= 1) {
            double od = __shfl_xor(bestd, off, 64);
            int    oi = __shfl_xor(besti, off, 64);
            float  ox = __shfl_xor(bx, off, 64);
            float  oy = __shfl_xor(by, off, 64);
            float  oz = __shfl_xor(bz, off, 64);
            if (od > bestd || (od == bestd && oi < besti)) {
                bestd = od; besti = oi; bx = ox; by = oy; bz = oz;
            }
        }
        const int wid  = tid >> 6;
        const int lane = tid & 63;
        if (lane == 0) {
            s_wd[wid] = bestd; s_wi[wid] = besti;
            s_wx[wid] = bx; s_wy[wid] = by; s_wz[wid] = bz;
        }
        __syncthreads();   // (A)

        Slot* sb = &slots[((size_t)(it & 1) * BATCH + b) * NBLK];

        // --- wave 0: block reduce (lanes 0..7), publish, gather peers, broadcast ---
        if (wid == 0) {
            double vd = -1.0; int vi = 0x7FFFFFFF;
            float  vx = 0.f, vy = 0.f, vz = 0.f;
            if (lane < NWAVES) {
                vd = s_wd[lane]; vi = s_wi[lane];
                vx = s_wx[lane]; vy = s_wy[lane]; vz = s_wz[lane];
            }
#pragma unroll
            for (int off = 4; off > 0; off >>= 1) {
                double od = __shfl_xor(vd, off, 64);
                int    oi = __shfl_xor(vi, off, 64);
                float  ox = __shfl_xor(vx, off, 64);
                float  oy = __shfl_xor(vy, off, 64);
                float  oz = __shfl_xor(vz, off, 64);
                if (od > vd || (od == vd && oi < vi)) {
                    vd = od; vi = oi; vx = ox; vy = oy; vz = oz;
                }
            }
            if (lane == 0) {   // publish this block's candidate
                Slot* s = sb + blk;
                s->dbits = (u64)__double_as_longlong(vd);
                s->x = vx; s->y = vy; s->z = vz;
                __hip_atomic_store(&s->tag,
                                   ((u64)(uint32_t)(it + 1) << 32) | (uint32_t)vi,
                                   __ATOMIC_RELEASE, __HIP_MEMORY_SCOPE_AGENT);
            }
            if (lane < NBLK) {   // wave-parallel gather: one spin per peer slot
                Slot* s = sb + lane;
                u64 t;
                do {
                    t = __hip_atomic_load(&s->tag, __ATOMIC_ACQUIRE, __HIP_MEMORY_SCOPE_AGENT);
                } while ((uint32_t)(t >> 32) != (uint32_t)(it + 1));
                double gd = __longlong_as_double((long long)s->dbits);
                int    gi = (int)(uint32_t)t;
                float  gx = s->x, gy = s->y, gz = s->z;
#pragma unroll
                for (int off = 4; off > 0; off >>= 1) {
                    double od = __shfl_xor(gd, off, 64);
                    int    oi = __shfl_xor(gi, off, 64);
                    float  ox = __shfl_xor(gx, off, 64);
                    float  oy = __shfl_xor(gy, off, 64);
                    float  oz = __shfl_xor(gz, off, 64);
                    if (od > gd || (od == gd && oi < gi)) {
                        gd = od; gi = oi; gx = ox; gy = oy; gz = oz;
                    }
                }
                if (lane == 0) {
                    s_last[0] = gx; s_last[1] = gy; s_last[2] = gz;
                    if (blk == 0) {
                        size_t o_ = ((size_t)b * KOUT + (it + 1)) * 3;
                        out[o_ + 0] = gx; out[o_ + 1] = gy; out[o_ + 2] = gz;
                    }
                }
            }
        }
        __syncthreads();   // (B)
        lx = s_last[0]; ly = s_last[1]; lz = s_last[2];
    }
}

extern "C" void kernel_launch(void* const* d_in, const int* in_sizes, int n_in,
                              void* d_out, int out_size, void* d_ws, size_t ws_size,
                              hipStream_t stream) {
    const float* points   = (const float*)d_in[0];
    const int*   init_idx = (const int*)d_in[1];
    float*       out      = (float*)d_out;
    Slot*        slots    = (Slot*)d_ws;   // 2*32*8*32 B = 16 KB

    void* args[] = { (void*)&points, (void*)&init_idx, (void*)&out, (void*)&slots };
    // Cooperative launch solely for the co-residency guarantee (no grid.sync used).
    hipLaunchCooperativeKernel((const void*)fps_kernel,
                               dim3(BATCH * NBLK), dim3(TPB),
                               args, 0, stream);
}

// Round 8
// 9081.824 us; speedup vs baseline: 7.3988x; 1.2187x over previous
//
#include <hip/hip_runtime.h>
#include <stdint.h>

typedef unsigned long long u64;

#define BATCH 32
#define NPTS  131072
#define KOUT  1024
#define NBLK  8                       // blocks per batch
#define TPB   512
#define PPT   (NPTS / (NBLK * TPB))   // 32 points per thread
#define NWAVES (TPB / 64)             // 8

// One publication slot per (parity, batch, block). 32 B.
// tag = ((it+1)<<32) | best_idx, release-stored LAST. Parity double-buffer:
// slot[p] for iteration it (p=it&1) is only overwritten at it+2, by which time
// every peer has provably consumed it. 0xAA poison never matches a valid tag.
struct __align__(32) Slot {
    u64      tag;
    u64      dbits;     // f64 bits of block-best dist
    float    x, y, z;   // coords of block-best point (rides along)
    uint32_t pad;
};

__global__ __launch_bounds__(TPB, 2) void fps_kernel(
    const float* __restrict__ points,   // B*N*3 f32
    const int*   __restrict__ init_idx, // B
    float*       __restrict__ out,      // B*K*3 f32
    Slot*        __restrict__ slots)    // [2][BATCH][NBLK]
{
    const int gid = blockIdx.x;
    // Swizzle: a batch's 8 blocks share gid%8 (likely same XCD). Bijective.
    const int b   = (gid >> 6) * 8 + (gid & 7);
    const int blk = (gid & 63) >> 3;
    const int tid = threadIdx.x;
    const float* bp = points + (size_t)b * NPTS * 3;

    // Persistent per-thread state: 32 points (f32, 96 VGPR) + 32 dists (f64, 64 VGPR).
    float  px[PPT], py[PPT], pz[PPT];
    double dist[PPT];
    const int nbase = blk * (NPTS / NBLK) + tid;   // + j*TPB, strided for coalescing
#pragma unroll
    for (int j = 0; j < PPT; ++j) {
        int n = nbase + j * TPB;
        px[j]   = bp[(size_t)n * 3 + 0];
        py[j]   = bp[(size_t)n * 3 + 1];
        pz[j]   = bp[(size_t)n * 3 + 2];
        dist[j] = 1e10;   // INF
    }
    // Opacity barrier: compiler may NOT rematerialize these as per-iteration
    // global reloads (round 7: VGPR=128, 15 MB/iter re-fetch). Forces true
    // register residency for the 1023-iteration reuse.
#pragma unroll
    for (int j = 0; j < PPT; ++j) {
        asm volatile("" : "+v"(px[j]), "+v"(py[j]), "+v"(pz[j]));
    }

    __shared__ float  s_last[3];
    __shared__ double s_wd[NWAVES];
    __shared__ int    s_wi[NWAVES];
    __shared__ float  s_wx[NWAVES], s_wy[NWAVES], s_wz[NWAVES];

    const int last = init_idx[b];
    if (blk == 0 && tid < 3) {
        out[((size_t)b * KOUT) * 3 + tid] = bp[(size_t)last * 3 + tid];
    }
    float lx = bp[(size_t)last * 3 + 0];
    float ly = bp[(size_t)last * 3 + 1];
    float lz = bp[(size_t)last * 3 + 2];

    for (int it = 0; it < KOUT - 1; ++it) {
        const double lxd = (double)lx, lyd = (double)ly, lzd = (double)lz;

        // --- register-local dist update + argmax (f64, bit-identical to np float64;
        //     DO NOT alter the arithmetic expression tree — validated absmax 0.0) ---
        double bestd = -1.0;
        int    besti = 0;
        float  bx = 0.f, by = 0.f, bz = 0.f;
#pragma unroll
        for (int j = 0; j < PPT; ++j) {
            double dx = (double)px[j] - lxd;
            double dy = (double)py[j] - lyd;
            double dz = (double)pz[j] - lzd;
            double d2 = dx * dx + dy * dy + dz * dz;
            double nd = fmin(dist[j], d2);
            dist[j] = nd;
            if (nd > bestd) {
                bestd = nd; besti = nbase + j * TPB;   // ascending idx => first max
                bx = px[j]; by = py[j]; bz = pz[j];
            }
        }

        // --- wave butterfly reduce (64 lanes), (dist,idx) lexicographic, coords ride ---
#pragma unroll
        for (int off = 32; off > 0; off >>= 1) {
            double od = __shfl_xor(bestd, off, 64);
            int    oi = __shfl_xor(besti, off, 64);
            float  ox = __shfl_xor(bx, off, 64);
            float  oy = __shfl_xor(by, off, 64);
            float  oz = __shfl_xor(bz, off, 64);
            if (od > bestd || (od == bestd && oi < besti)) {
                bestd = od; besti = oi; bx = ox; by = oy; bz = oz;
            }
        }
        const int wid  = tid >> 6;
        const int lane = tid & 63;
        if (lane == 0) {
            s_wd[wid] = bestd; s_wi[wid] = besti;
            s_wx[wid] = bx; s_wy[wid] = by; s_wz[wid] = bz;
        }
        __syncthreads();   // (A)

        Slot* sb = &slots[((size_t)(it & 1) * BATCH + b) * NBLK];

        // --- wave 0: block reduce (lanes 0..7), publish, gather peers, broadcast ---
        if (wid == 0) {
            double vd = -1.0; int vi = 0x7FFFFFFF;
            float  vx = 0.f, vy = 0.f, vz = 0.f;
            if (lane < NWAVES) {
                vd = s_wd[lane]; vi = s_wi[lane];
                vx = s_wx[lane]; vy = s_wy[lane]; vz = s_wz[lane];
            }
#pragma unroll
            for (int off = 4; off > 0; off >>= 1) {
                double od = __shfl_xor(vd, off, 64);
                int    oi = __shfl_xor(vi, off, 64);
                float  ox = __shfl_xor(vx, off, 64);
                float  oy = __shfl_xor(vy, off, 64);
                float  oz = __shfl_xor(vz, off, 64);
                if (od > vd || (od == vd && oi < vi)) {
                    vd = od; vi = oi; vx = ox; vy = oy; vz = oz;
                }
            }
            if (lane == 0) {   // publish this block's candidate
                Slot* s = sb + blk;
                s->dbits = (u64)__double_as_longlong(vd);
                s->x = vx; s->y = vy; s->z = vz;
                __hip_atomic_store(&s->tag,
                                   ((u64)(uint32_t)(it + 1) << 32) | (uint32_t)vi,
                                   __ATOMIC_RELEASE, __HIP_MEMORY_SCOPE_AGENT);
            }
            if (lane < NBLK) {   // wave-parallel gather: one spin per peer slot
                Slot* s = sb + lane;
                u64 t;
                do {
                    t = __hip_atomic_load(&s->tag, __ATOMIC_ACQUIRE, __HIP_MEMORY_SCOPE_AGENT);
                } while ((uint32_t)(t >> 32) != (uint32_t)(it + 1));
                double gd = __longlong_as_double((long long)s->dbits);
                int    gi = (int)(uint32_t)t;
                float  gx = s->x, gy = s->y, gz = s->z;
#pragma unroll
                for (int off = 4; off > 0; off >>= 1) {
                    double od = __shfl_xor(gd, off, 64);
                    int    oi = __shfl_xor(gi, off, 64);
                    float  ox = __shfl_xor(gx, off, 64);
                    float  oy = __shfl_xor(gy, off, 64);
                    float  oz = __shfl_xor(gz, off, 64);
                    if (od > gd || (od == gd && oi < gi)) {
                        gd = od; gi = oi; gx = ox; gy = oy; gz = oz;
                    }
                }
                if (lane == 0) {
                    s_last[0] = gx; s_last[1] = gy; s_last[2] = gz;
                    if (blk == 0) {
                        size_t o_ = ((size_t)b * KOUT + (it + 1)) * 3;
                        out[o_ + 0] = gx; out[o_ + 1] = gy; out[o_ + 2] = gz;
                    }
                }
            }
        }
        __syncthreads();   // (B)
        lx = s_last[0]; ly = s_last[1]; lz = s_last[2];
    }
}

extern "C" void kernel_launch(void* const* d_in, const int* in_sizes, int n_in,
                              void* d_out, int out_size, void* d_ws, size_t ws_size,
                              hipStream_t stream) {
    const float* points   = (const float*)d_in[0];
    const int*   init_idx = (const int*)d_in[1];
    float*       out      = (float*)d_out;
    Slot*        slots    = (Slot*)d_ws;   // 2*32*8*32 B = 16 KB

    void* args[] = { (void*)&points, (void*)&init_idx, (void*)&out, (void*)&slots };
    // Cooperative launch solely for the co-residency guarantee (no grid.sync used).
    hipLaunchCooperativeKernel((const void*)fps_kernel,
                               dim3(BATCH * NBLK), dim3(TPB),
                               args, 0, stream);
}

// Round 11
// 5257.336 us; speedup vs baseline: 12.7811x; 1.7275x over previous
//
#include <hip/hip_runtime.h>
#include <stdint.h>

typedef unsigned long long u64;

#define BATCH 32
#define NPTS  131072
#define KOUT  1024
#define NBLK  8                       // blocks per batch
#define TPB   512
#define PPT   (NPTS / (NBLK * TPB))   // 32 points per thread
#define NWAVES (TPB / 64)             // 8

// Publication slot per (parity, batch, block): three SELF-VALIDATING u64 words,
// each = (r<<32) | payload32, r = it+1 in [1,1023]. Reader spins with RELAXED
// agent loads until hi32==r on all three -> no acquire/release (no buffer_inv /
// L2 writeback per op, which was round 8's 7 us/iter cost). Parity reuse (r vs
// r-2) and 0xAA poison both fail the hi32==r check. Overwrite at r+2 is safe:
// publishing r+2 requires having consumed ALL peers' r+1, which requires those
// peers to have consumed r (data dependency through the dist update).
struct __align__(32) Slot {
    u64 w0;   // (r<<32) | hi32(f64 dist bits)
    u64 w1;   // (r<<32) | lo32(f64 dist bits)
    u64 w2;   // (r<<32) | best idx
    u64 pad;
};

__global__ __launch_bounds__(TPB, 2) void fps_kernel(
    const float* __restrict__ points,   // B*N*3 f32
    const int*   __restrict__ init_idx, // B
    float*       __restrict__ out,      // B*K*3 f32
    Slot*        __restrict__ slots)    // [2][BATCH][NBLK]
{
    const int gid = blockIdx.x;
    // Swizzle: a batch's 8 blocks share gid%8 (likely same XCD). Bijective.
    const int b   = (gid >> 6) * 8 + (gid & 7);
    const int blk = (gid & 63) >> 3;
    const int tid = threadIdx.x;
    const float* bp = points + (size_t)b * NPTS * 3;

    // Persistent per-thread state: 32 points (f32) + 32 running dists (f64).
    float  px[PPT], py[PPT], pz[PPT];
    double dist[PPT];
    const int nbase = blk * (NPTS / NBLK) + tid;   // + j*TPB, strided for coalescing
#pragma unroll
    for (int j = 0; j < PPT; ++j) {
        int n = nbase + j * TPB;
        px[j]   = bp[(size_t)n * 3 + 0];
        py[j]   = bp[(size_t)n * 3 + 1];
        pz[j]   = bp[(size_t)n * 3 + 2];
        dist[j] = 1e10;   // INF
    }
    // Opacity barrier: forbid rematerialization as per-iteration global reloads
    // (round 7: 15 MB/iter re-fetch). Verified round 8: FETCH 15.2 GB -> 37 MB.
#pragma unroll
    for (int j = 0; j < PPT; ++j) {
        asm volatile("" : "+v"(px[j]), "+v"(py[j]), "+v"(pz[j]));
    }

    __shared__ float  s_last[3];
    __shared__ double s_wd[NWAVES];
    __shared__ int    s_wi[NWAVES];

    const int last = init_idx[b];
    if (blk == 0 && tid < 3) {
        out[((size_t)b * KOUT) * 3 + tid] = bp[(size_t)last * 3 + tid];
    }
    float lx = bp[(size_t)last * 3 + 0];
    float ly = bp[(size_t)last * 3 + 1];
    float lz = bp[(size_t)last * 3 + 2];

    for (int it = 0; it < KOUT - 1; ++it) {
        const double lxd = (double)lx, lyd = (double)ly, lzd = (double)lz;

        // --- register-local dist update + argmax (f64, bit-identical to np float64;
        //     DO NOT alter the arithmetic expression tree — validated absmax 0.0) ---
        double bestd = -1.0;
        int    besti = 0;
#pragma unroll
        for (int j = 0; j < PPT; ++j) {
            double dx = (double)px[j] - lxd;
            double dy = (double)py[j] - lyd;
            double dz = (double)pz[j] - lzd;
            double d2 = dx * dx + dy * dy + dz * dz;
            double nd = fmin(dist[j], d2);
            dist[j] = nd;
            if (nd > bestd) { bestd = nd; besti = nbase + j * TPB; }  // first max
        }

        // --- wave butterfly reduce (64 lanes), (dist,idx) lexicographic ---
#pragma unroll
        for (int off = 32; off > 0; off >>= 1) {
            double od = __shfl_xor(bestd, off, 64);
            int    oi = __shfl_xor(besti, off, 64);
            if (od > bestd || (od == bestd && oi < besti)) { bestd = od; besti = oi; }
        }
        const int wid  = tid >> 6;
        const int lane = tid & 63;
        if (lane == 0) { s_wd[wid] = bestd; s_wi[wid] = besti; }
        __syncthreads();   // (A)

        const u64  r  = (u64)(uint32_t)(it + 1);
        const u64  rh = r << 32;
        Slot* sb = &slots[((size_t)(it & 1) * BATCH + b) * NBLK];

        // --- wave 0: block reduce (lanes 0..7), publish, gather peers, broadcast ---
        if (wid == 0) {
            double vd = -1.0; int vi = 0x7FFFFFFF;
            if (lane < NWAVES) { vd = s_wd[lane]; vi = s_wi[lane]; }
#pragma unroll
            for (int off = 4; off > 0; off >>= 1) {
                double od = __shfl_xor(vd, off, 64);
                int    oi = __shfl_xor(vi, off, 64);
                if (od > vd || (od == vd && oi < vi)) { vd = od; vi = oi; }
            }
            if (lane == 0) {   // publish: three relaxed self-validating words
                Slot* s = sb + blk;
                u64 d64 = (u64)__double_as_longlong(vd);
                __hip_atomic_store(&s->w0, rh | (d64 >> 32),
                                   __ATOMIC_RELAXED, __HIP_MEMORY_SCOPE_AGENT);
                __hip_atomic_store(&s->w1, rh | (d64 & 0xFFFFFFFFull),
                                   __ATOMIC_RELAXED, __HIP_MEMORY_SCOPE_AGENT);
                __hip_atomic_store(&s->w2, rh | (u64)(uint32_t)vi,
                                   __ATOMIC_RELAXED, __HIP_MEMORY_SCOPE_AGENT);
            }
            if (lane < NBLK) {   // gather: one spin per peer slot, relaxed loads
                Slot* s = sb + lane;
                u64 a, c, d;
                do {
                    a = __hip_atomic_load(&s->w0, __ATOMIC_RELAXED, __HIP_MEMORY_SCOPE_AGENT);
                    c = __hip_atomic_load(&s->w1, __ATOMIC_RELAXED, __HIP_MEMORY_SCOPE_AGENT);
                    d = __hip_atomic_load(&s->w2, __ATOMIC_RELAXED, __HIP_MEMORY_SCOPE_AGENT);
                } while ((a >> 32) != r || (c >> 32) != r || (d >> 32) != r);
                u64 gd = (a << 32) | (c & 0xFFFFFFFFull);   // f64 bits; >=0 so u64 cmp == f64 cmp
                int gi = (int)(uint32_t)d;
                // speculative coord fetch for THIS candidate (read-only data, no sync
                // needed); winner's coords selected by the shuffle reduce below.
                float gx = bp[(size_t)gi * 3 + 0];
                float gy = bp[(size_t)gi * 3 + 1];
                float gz = bp[(size_t)gi * 3 + 2];
#pragma unroll
                for (int off = 4; off > 0; off >>= 1) {
                    u64   od = (u64)__shfl_xor((long long)gd, off, 64);
                    int   oi = __shfl_xor(gi, off, 64);
                    float ox = __shfl_xor(gx, off, 64);
                    float oy = __shfl_xor(gy, off, 64);
                    float oz = __shfl_xor(gz, off, 64);
                    if (od > gd || (od == gd && oi < gi)) {
                        gd = od; gi = oi; gx = ox; gy = oy; gz = oz;
                    }
                }
                if (lane == 0) {
                    s_last[0] = gx; s_last[1] = gy; s_last[2] = gz;
                    if (blk == 0) {
                        size_t o_ = ((size_t)b * KOUT + (it + 1)) * 3;
                        out[o_ + 0] = gx; out[o_ + 1] = gy; out[o_ + 2] = gz;
                    }
                }
            }
        }
        __syncthreads();   // (B)
        lx = s_last[0]; ly = s_last[1]; lz = s_last[2];
    }
}

extern "C" void kernel_launch(void* const* d_in, const int* in_sizes, int n_in,
                              void* d_out, int out_size, void* d_ws, size_t ws_size,
                              hipStream_t stream) {
    const float* points   = (const float*)d_in[0];
    const int*   init_idx = (const int*)d_in[1];
    float*       out      = (float*)d_out;
    Slot*        slots    = (Slot*)d_ws;   // 2*32*8*32 B = 16 KB

    void* args[] = { (void*)&points, (void*)&init_idx, (void*)&out, (void*)&slots };
    // Cooperative launch solely for the co-residency guarantee (no grid.sync used).
    hipLaunchCooperativeKernel((const void*)fps_kernel,
                               dim3(BATCH * NBLK), dim3(TPB),
                               args, 0, stream);
}